// Round 4
// baseline (226.983 us; speedup 1.0000x reference)
//
#include <hip/hip_runtime.h>

#define DEV __device__ __forceinline__

typedef __bf16 bf16x8 __attribute__((ext_vector_type(8)));
typedef float f32x4 __attribute__((ext_vector_type(4)));
typedef short s16x8 __attribute__((ext_vector_type(8)));
typedef unsigned short u16;

static constexpr int D = 1024;
static constexpr int M = 16384;   // 8*2048 rows
static constexpr int R = 64;      // rows per block
static constexpr float EPS = 1e-8f;

DEV u16 f2bf(float f) {
  union { float f; unsigned u; } v; v.f = f;
  unsigned u = v.u;
  return (u16)((u + 0x7FFFu + ((u >> 16) & 1u)) >> 16);  // RNE
}

DEV void async_copy16(const void* g, void* l) {
  __builtin_amdgcn_global_load_lds(
      (const __attribute__((address_space(1))) void*)g,
      (__attribute__((address_space(3))) void*)l, 16, 0, 0);
}

// ---------------- prep: pm[k][n] f32 -> bt[n][k] bf16 ----------------
__global__ __launch_bounds__(256) void k_transpose(const float* __restrict__ pm,
                                                   u16* __restrict__ bt) {
  __shared__ float t[32][33];
  int bx = blockIdx.x * 32, by = blockIdx.y * 32;
  int tx = threadIdx.x, ty = threadIdx.y;  // 32 x 8
#pragma unroll
  for (int j = 0; j < 32; j += 8)
    t[ty + j][tx] = pm[(size_t)(by + ty + j) * D + bx + tx];
  __syncthreads();
#pragma unroll
  for (int j = 0; j < 32; j += 8)
    bt[(size_t)(bx + ty + j) * D + by + tx] = f2bf(t[tx][ty + j]);
}

// ---------------- fused: coherence + GEMM + rotation + LayerNorm ----------------
// 8 waves (512 thr) per block -> 2 waves/SIMD so latency can be co-scheduled.
// One block per 64-row panel; A staged once (128 KB, fragment-major); B streamed
// via global_load_lds into a double-buffered 8 KB tile; one barrier per k-step.
// Fragment scheme (rounds 2-3 verified): unit(row,kg) 16B; af row=rb*16+l15,
// kg=l4; bf col=cb*16+l15, kg=l4; C row=l4*4+reg, col=l15.
__global__ __launch_bounds__(512, 2) void k_fused(
    const float* __restrict__ xr, const float* __restrict__ xi,
    const u16* __restrict__ bt, const float* __restrict__ cfp,
    const float* __restrict__ lw, const float* __restrict__ lb,
    float* __restrict__ outR, float* __restrict__ outI) {
  __shared__ __align__(16) u16 A_lds[32 * 256 * 8];  // 128 KB: 32 kk-chunks x 256 units
  __shared__ __align__(16) u16 B_lds[2 * 512 * 8];   // 16 KB: 2 bufs x 512 units
  __shared__ float scale_lds[R];

  const int tid = threadIdx.x;
  const int lane = tid & 63;
  const int l15 = lane & 15, l4 = lane >> 4;
  const int wid = tid >> 6;               // 8 waves
  const int wr = wid >> 2, wc = wid & 3;  // 2x4 wave grid, wave tile 32x32
  const size_t row0 = (size_t)blockIdx.x * R;
  const float cf = cfp[0];

  // ---- phase 0: stage A (f32 -> bf16, fragment-major) + per-row coherence ----
  {
    int row = tid >> 3;  // 0..63
    int s8 = tid & 7;    // 8 threads per row
    const float* xrp = xr + (row0 + row) * D;
    const float* xip = xi + (row0 + row) * D;
    float sc = 0.f, ss = 0.f;
#pragma unroll 4
    for (int step = 0; step < 16; ++step) {
      int p = s8 + step * 8;  // 8-float group 0..127
      f32x4 a0 = *(const f32x4*)(xrp + p * 8);
      f32x4 a1 = *(const f32x4*)(xrp + p * 8 + 4);
      f32x4 b0 = *(const f32x4*)(xip + p * 8);
      f32x4 b1 = *(const f32x4*)(xip + p * 8 + 4);
      float fx[8] = {a0.x, a0.y, a0.z, a0.w, a1.x, a1.y, a1.z, a1.w};
      float fy[8] = {b0.x, b0.y, b0.z, b0.w, b1.x, b1.y, b1.z, b1.w};
      s16x8 v;
#pragma unroll
      for (int j = 0; j < 8; ++j) {
        float x = fx[j] + EPS, y = fy[j] + EPS;
        float inv = rsqrtf(x * x + y * y);
        sc += x * inv;
        ss += y * inv;
        v[j] = (short)f2bf(fx[j]);
      }
      int u = (p >> 2) * 256 + (row >> 4) * 64 + (p & 3) * 16 + (row & 15);
      *(s16x8*)&A_lds[u * 8] = v;
    }
    sc += __shfl_xor(sc, 1, 64); sc += __shfl_xor(sc, 2, 64); sc += __shfl_xor(sc, 4, 64);
    ss += __shfl_xor(ss, 1, 64); ss += __shfl_xor(ss, 2, 64); ss += __shfl_xor(ss, 4, 64);
    if (s8 == 0) {
      float coh = (sc * sc + ss * ss) * (1.0f / (1024.0f * 1024.0f));
      scale_lds[row] = cf * (1.0f - coh);
    }
  }
  __syncthreads();

  // ---- GEMM: 256 steps (tn = s>>5, kk = s&31), dbuf B via global_load_lds ----
  f32x4 acc[2][2] = {};

  // stage B tile for step s into buf: 512 lanes x 16B, wave-linear LDS dest.
  auto stage = [&](int buf, int s) {
    int tn = s >> 5, kk = s & 31;
    int col = wid * 16 + l15;  // unit = wid*64 + lane -> col = wid*16+l15, kg = l4
    const u16* gsrc = bt + (size_t)(tn * 128 + col) * D + kk * 32 + l4 * 8;
    async_copy16(gsrc, &B_lds[(buf * 512 + wid * 64) * 8]);
  };

  stage(0, 0);
  __syncthreads();

  for (int s_ = 0; s_ < 256; ++s_) {
    if (s_ + 1 < 256) stage((s_ + 1) & 1, s_ + 1);

    {  // compute step s_
      int kk = s_ & 31, buf = s_ & 1;
      bf16x8 af[2], bf[2];
#pragma unroll
      for (int mf = 0; mf < 2; ++mf) {
        int u = kk * 256 + (wr * 2 + mf) * 64 + l4 * 16 + l15;
        af[mf] = __builtin_bit_cast(bf16x8, *(const s16x8*)&A_lds[u * 8]);
      }
#pragma unroll
      for (int nf = 0; nf < 2; ++nf) {
        int u = buf * 512 + (wc * 2 + nf) * 64 + l4 * 16 + l15;
        bf[nf] = __builtin_bit_cast(bf16x8, *(const s16x8*)&B_lds[u * 8]);
      }
#pragma unroll
      for (int mf = 0; mf < 2; ++mf)
#pragma unroll
        for (int nf = 0; nf < 2; ++nf)
          acc[mf][nf] = __builtin_amdgcn_mfma_f32_16x16x32_bf16(af[mf], bf[nf], acc[mf][nf], 0, 0, 0);
    }

    if ((s_ & 31) == 31) {  // epilogue for tn: rotate + normalize + store
      int tn = s_ >> 5;
#pragma unroll
      for (int mf = 0; mf < 2; ++mf) {
#pragma unroll
        for (int i = 0; i < 4; ++i) {
          int row_l = wr * 32 + mf * 16 + l4 * 4 + i;
          float scl = scale_lds[row_l];
          const float* xrp = xr + (row0 + row_l) * D;
          const float* xip = xi + (row0 + row_l) * D;
          float* orp = outR + (row0 + row_l) * D;
          float* oip = outI + (row0 + row_l) * D;
#pragma unroll
          for (int nf = 0; nf < 2; ++nf) {
            int gcol = tn * 128 + wc * 32 + nf * 16 + l15;
            float t = acc[mf][nf][i] * scl;
            float sn, cs;
            __sincosf(t, &sn, &cs);
            float a = xrp[gcol], b = xip[gcol];
            float nr = a * cs - b * sn;
            float ni = a * sn + b * cs;
            float inv = rsqrtf(nr * nr + ni * ni + EPS);
            orp[gcol] = nr * inv;
            oip[gcol] = ni * inv;
          }
        }
      }
#pragma unroll
      for (int mf = 0; mf < 2; ++mf)
#pragma unroll
        for (int nf = 0; nf < 2; ++nf)
          acc[mf][nf] = f32x4{0.f, 0.f, 0.f, 0.f};
    }
    __syncthreads();
  }

  // ---- phase 2: LayerNorm over this block's 128 output rows (L2/L3-hot) ----
  for (int rr = wid; rr < 2 * R; rr += 8) {
    float* base = (rr < R) ? (outR + (row0 + rr) * D) : (outI + (row0 + rr - R) * D);
    f32x4 v[4];
    float sum = 0.f, sq = 0.f;
#pragma unroll
    for (int c = 0; c < 4; ++c) {
      v[c] = ((const f32x4*)base)[c * 64 + lane];
#pragma unroll
      for (int j = 0; j < 4; ++j) { sum += v[c][j]; sq += v[c][j] * v[c][j]; }
    }
#pragma unroll
    for (int off = 1; off < 64; off <<= 1) {
      sum += __shfl_xor(sum, off, 64);
      sq += __shfl_xor(sq, off, 64);
    }
    float mu = sum * (1.0f / D);
    float rsd = rsqrtf(sq * (1.0f / D) - mu * mu + EPS);
#pragma unroll
    for (int c = 0; c < 4; ++c) {
      f32x4 w4 = ((const f32x4*)lw)[c * 64 + lane];
      f32x4 b4 = ((const f32x4*)lb)[c * 64 + lane];
      f32x4 o;
#pragma unroll
      for (int j = 0; j < 4; ++j) o[j] = (v[c][j] - mu) * rsd * w4[j] + b4[j];
      ((f32x4*)base)[c * 64 + lane] = o;
    }
  }
}

extern "C" void kernel_launch(void* const* d_in, const int* in_sizes, int n_in,
                              void* d_out, int out_size, void* d_ws, size_t ws_size,
                              hipStream_t stream) {
  const float* xr = (const float*)d_in[0];
  const float* xi = (const float*)d_in[1];
  const float* pm = (const float*)d_in[2];
  const float* cf = (const float*)d_in[3];
  const float* lw = (const float*)d_in[4];
  const float* lb = (const float*)d_in[5];
  float* outR = (float*)d_out;
  float* outI = outR + (size_t)M * D;
  u16* bt = (u16*)d_ws;  // 2 MB bf16 B^T

  k_transpose<<<dim3(32, 32), dim3(32, 8), 0, stream>>>(pm, bt);
  k_fused<<<M / R, 512, 0, stream>>>(xr, xi, bt, cf, lw, lb, outR, outI);
}

// Round 5
// 137.014 us; speedup vs baseline: 1.6566x; 1.6566x over previous
//
#include <hip/hip_runtime.h>
#include <hip/hip_fp16.h>

#define DEV __device__ __forceinline__

typedef __bf16 bf16x8 __attribute__((ext_vector_type(8)));
typedef float f32x4 __attribute__((ext_vector_type(4)));
typedef short s16x8 __attribute__((ext_vector_type(8)));
typedef unsigned short u16;

static constexpr int D = 1024;
static constexpr int M = 16384;   // 8*2048 rows
static constexpr int R = 32;      // rows per block
static constexpr float EPS = 1e-8f;
static constexpr int PAD = 1028;  // half2 stride of stash rows (16B-aligned, low-conflict)

// LDS carve (bytes): GEMM: A [0,64K), B dbuf [64K,128K). P2: stash [0,131584),
// red [131584,135680), stats [135680,136192).
static constexpr int SMEM_BYTES = 136192;
static constexpr int B_OFF_U16 = 32768;      // u16 index of B_lds
static constexpr int RED_OFF = 131584;
static constexpr int STATS_OFF = 135680;

DEV u16 f2bf(float f) {
  union { float f; unsigned u; } v; v.f = f;
  unsigned u = v.u;
  return (u16)((u + 0x7FFFu + ((u >> 16) & 1u)) >> 16);  // RNE
}

DEV void async_copy16(const void* g, void* l) {
  __builtin_amdgcn_global_load_lds(
      (const __attribute__((address_space(1))) void*)g,
      (__attribute__((address_space(3))) void*)l, 16, 0, 0);
}

union H2x4 { s16x8 v; __half2 h[4]; };

// ---------------- prep: pm[k][n] f32 -> bt in GEMM-chunk LDS-image layout ----------------
// chunk ch = kk*2 + nh (32 KB each): unit u = cb*64 + kg*16 + c15 holds
// col = nh*512 + cb*16 + c15, k = kk*32 + kg*8 + j  (j = elem 0..7)
__global__ __launch_bounds__(256) void k_prep(const float* __restrict__ pm,
                                              u16* __restrict__ bt) {
  __shared__ float t[32][33];
  int bx = blockIdx.x * 32, by = blockIdx.y * 32;
  int tx = threadIdx.x, ty = threadIdx.y;  // 32 x 8
#pragma unroll
  for (int j = 0; j < 32; j += 8)
    t[ty + j][tx] = pm[(size_t)(by + ty + j) * D + bx + tx];
  __syncthreads();
#pragma unroll
  for (int j = 0; j < 32; j += 8) {
    int col = bx + ty + j, k = by + tx;
    int kk = k >> 5, nh = col >> 9, cb = (col >> 4) & 31, c15 = col & 15;
    int kg = (k >> 3) & 3, je = k & 7;
    bt[(size_t)(kk * 2 + nh) * 16384 + (size_t)((cb * 64 + kg * 16 + c15) * 8 + je)] =
        f2bf(t[tx][ty + j]);
  }
}

// ---------------- fused: stage A + GEMM (counted vmcnt) + coherence + rotate + LN ----------------
__global__ __launch_bounds__(512, 2) void k_fused(
    const float* __restrict__ xr, const float* __restrict__ xi,
    const u16* __restrict__ bt, const float* __restrict__ cfp,
    const float* __restrict__ lw, const float* __restrict__ lb,
    float* __restrict__ outR, float* __restrict__ outI) {
  __shared__ __align__(16) unsigned char smem[SMEM_BYTES];
  u16* A_lds = (u16*)smem;                       // 4096 units x 16B
  u16* B_lds = (u16*)smem + B_OFF_U16;           // 2 bufs x 2048 units
  __half2* stash = (__half2*)smem;               // [32][PAD]
  float* red = (float*)(smem + RED_OFF);         // [32][8][4]
  float* stats = (float*)(smem + STATS_OFF);     // [32][4]

  const int tid = threadIdx.x;
  const int lane = tid & 63;
  const int l15 = lane & 15, l4 = lane >> 4;
  const int wv = tid >> 6;  // 8 waves, wave grid 1x8 (wave wv owns cols split below)
  const size_t row0 = (size_t)blockIdx.x * R;
  const float cfv = cfp[0];

  // ---- phase 0: stage A panel (xr only), f32 -> bf16, fragment-major + XOR swizzle ----
  {
    int row = tid >> 4;   // 0..31
    int s16 = tid & 15;
    const float* src = xr + (row0 + row) * D;
#pragma unroll
    for (int it = 0; it < 4; ++it)
#pragma unroll
      for (int h = 0; h < 2; ++h) {
        int kgl = it * 32 + s16 * 2 + h;  // global 8-float group 0..127
        f32x4 a = *(const f32x4*)(src + kgl * 8);
        f32x4 b = *(const f32x4*)(src + kgl * 8 + 4);
        s16x8 v;
        v[0] = (short)f2bf(a.x); v[1] = (short)f2bf(a.y);
        v[2] = (short)f2bf(a.z); v[3] = (short)f2bf(a.w);
        v[4] = (short)f2bf(b.x); v[5] = (short)f2bf(b.y);
        v[6] = (short)f2bf(b.z); v[7] = (short)f2bf(b.w);
        int kk = kgl >> 2, kg = kgl & 3;
        int u = kk * 128 + (row >> 4) * 64 + kg * 16 + ((row & 15) ^ (kk & 15));
        *(s16x8*)&A_lds[u * 8] = v;
      }
  }
  __syncthreads();

  // ---- GEMM: 64 substeps (kk 0..31 x nh 0..1), dbuf B, counted vmcnt ----
  f32x4 acc[2][8] = {};  // [rb][nh*4+nf]

  auto stage = [&](int buf, int s) {
    const u16* src = bt + (size_t)s * 16384;
    u16* dst = &B_lds[buf * 16384];
#pragma unroll
    for (int i = 0; i < 4; ++i) {
      int off = ((wv * 4 + i) * 64 + lane) * 8;
      async_copy16(src + off, dst + off);
    }
  };

  stage(0, 0);
  asm volatile("s_waitcnt vmcnt(0)" ::: "memory");
  __builtin_amdgcn_s_barrier();

  for (int kk = 0; kk < 32; ++kk) {
    bf16x8 af[2];
#pragma unroll
    for (int rb = 0; rb < 2; ++rb) {
      int u = kk * 128 + rb * 64 + l4 * 16 + (l15 ^ (kk & 15));
      af[rb] = __builtin_bit_cast(bf16x8, *(const s16x8*)&A_lds[u * 8]);
    }
#pragma unroll
    for (int nh = 0; nh < 2; ++nh) {
      int s = kk * 2 + nh;
      if (s < 63) {
        stage((s + 1) & 1, s + 1);
        asm volatile("s_waitcnt vmcnt(4)" ::: "memory");
      } else {
        asm volatile("s_waitcnt vmcnt(0)" ::: "memory");
      }
      __builtin_amdgcn_s_barrier();
      const u16* bb = &B_lds[(s & 1) * 16384];
#pragma unroll
      for (int nf = 0; nf < 4; ++nf) {
        int u = (wv * 4 + nf) * 64 + l4 * 16 + l15;
        bf16x8 bf = __builtin_bit_cast(bf16x8, *(const s16x8*)&bb[u * 8]);
        acc[0][nh * 4 + nf] =
            __builtin_amdgcn_mfma_f32_16x16x32_bf16(af[0], bf, acc[0][nh * 4 + nf], 0, 0, 0);
        acc[1][nh * 4 + nf] =
            __builtin_amdgcn_mfma_f32_16x16x32_bf16(af[1], bf, acc[1][nh * 4 + nf], 0, 0, 0);
      }
      __builtin_amdgcn_s_barrier();
    }
  }
  __syncthreads();  // GEMM done; repurpose LDS

  // ---- P2a: load (a,b) once, coherence partials, stash f16 ----
  float sc8[8], ss8[8];
#pragma unroll
  for (int p = 0; p < 8; ++p) { sc8[p] = 0.f; ss8[p] = 0.f; }
#pragma unroll
  for (int rb = 0; rb < 2; ++rb)
#pragma unroll
    for (int i = 0; i < 4; ++i) {
      const int p = rb * 4 + i;
      const int row_l = rb * 16 + l4 * 4 + i;
      const float* ar = xr + (row0 + row_l) * D;
      const float* ai = xi + (row0 + row_l) * D;
#pragma unroll
      for (int q = 0; q < 8; ++q) {
        int col = (q >> 2) * 512 + wv * 64 + (q & 3) * 16 + l15;
        float a = ar[col], b = ai[col];
        float xe = a + EPS, ye = b + EPS;
        float inv = rsqrtf(xe * xe + ye * ye);
        sc8[p] += xe * inv;
        ss8[p] += ye * inv;
        stash[row_l * PAD + col] = __floats2half2_rn(a, b);
      }
    }
#pragma unroll
  for (int p = 0; p < 8; ++p)
#pragma unroll
    for (int d = 1; d < 16; d <<= 1) {
      sc8[p] += __shfl_xor(sc8[p], d, 64);
      ss8[p] += __shfl_xor(ss8[p], d, 64);
    }
  if (l15 == 0) {
#pragma unroll
    for (int rb = 0; rb < 2; ++rb)
#pragma unroll
      for (int i = 0; i < 4; ++i) {
        int p = rb * 4 + i, row_l = rb * 16 + l4 * 4 + i;
        red[(row_l * 8 + wv) * 4 + 0] = sc8[p];
        red[(row_l * 8 + wv) * 4 + 1] = ss8[p];
      }
  }
  __syncthreads();
  float srow[8];
#pragma unroll
  for (int rb = 0; rb < 2; ++rb)
#pragma unroll
    for (int i = 0; i < 4; ++i) {
      int p = rb * 4 + i, row_l = rb * 16 + l4 * 4 + i;
      float tsc = 0.f, tss = 0.f;
#pragma unroll
      for (int w8 = 0; w8 < 8; ++w8) {
        tsc += red[(row_l * 8 + w8) * 4 + 0];
        tss += red[(row_l * 8 + w8) * 4 + 1];
      }
      float coh = (tsc * tsc + tss * tss) * (1.0f / (1024.0f * 1024.0f));
      srow[p] = cfv * (1.0f - coh);
    }
  __syncthreads();  // red reuse barrier

  // ---- P2b: rotate + normalize (poly sincos), stash rotated f16, LN partials ----
  float snr[8], sqr[8], sni[8], sqi[8];
#pragma unroll
  for (int p = 0; p < 8; ++p) { snr[p] = 0.f; sqr[p] = 0.f; sni[p] = 0.f; sqi[p] = 0.f; }
#pragma unroll
  for (int rb = 0; rb < 2; ++rb)
#pragma unroll
    for (int i = 0; i < 4; ++i) {
      const int p = rb * 4 + i;
      const int row_l = rb * 16 + l4 * 4 + i;
      const float sr = srow[p];
#pragma unroll
      for (int q = 0; q < 8; ++q) {
        int col = (q >> 2) * 512 + wv * 64 + (q & 3) * 16 + l15;
        float t = acc[rb][q][i] * sr;
        float t2 = t * t;
        float sn = t * (1.f + t2 * (-1.f / 6.f + t2 * (1.f / 120.f - t2 * (1.f / 5040.f))));
        float cs = 1.f + t2 * (-0.5f + t2 * (1.f / 24.f - t2 * (1.f / 720.f)));
        __half2 ab = stash[row_l * PAD + col];
        float a = __low2float(ab), b = __high2float(ab);
        float nr = a * cs - b * sn;
        float ni = a * sn + b * cs;
        float inv = rsqrtf(nr * nr + ni * ni + EPS);
        nr *= inv; ni *= inv;
        stash[row_l * PAD + col] = __floats2half2_rn(nr, ni);
        snr[p] += nr; sqr[p] += nr * nr;
        sni[p] += ni; sqi[p] += ni * ni;
      }
    }
#pragma unroll
  for (int p = 0; p < 8; ++p)
#pragma unroll
    for (int d = 1; d < 16; d <<= 1) {
      snr[p] += __shfl_xor(snr[p], d, 64);
      sqr[p] += __shfl_xor(sqr[p], d, 64);
      sni[p] += __shfl_xor(sni[p], d, 64);
      sqi[p] += __shfl_xor(sqi[p], d, 64);
    }
  if (l15 == 0) {
#pragma unroll
    for (int rb = 0; rb < 2; ++rb)
#pragma unroll
      for (int i = 0; i < 4; ++i) {
        int p = rb * 4 + i, row_l = rb * 16 + l4 * 4 + i;
        red[(row_l * 8 + wv) * 4 + 0] = snr[p];
        red[(row_l * 8 + wv) * 4 + 1] = sqr[p];
        red[(row_l * 8 + wv) * 4 + 2] = sni[p];
        red[(row_l * 8 + wv) * 4 + 3] = sqi[p];
      }
  }
  __syncthreads();
  if (wv == 0 && l15 == 0) {
#pragma unroll
    for (int rb = 0; rb < 2; ++rb)
#pragma unroll
      for (int i = 0; i < 4; ++i) {
        int row_l = rb * 16 + l4 * 4 + i;
        float s0 = 0.f, s1 = 0.f, s2 = 0.f, s3 = 0.f;
#pragma unroll
        for (int w8 = 0; w8 < 8; ++w8) {
          s0 += red[(row_l * 8 + w8) * 4 + 0];
          s1 += red[(row_l * 8 + w8) * 4 + 1];
          s2 += red[(row_l * 8 + w8) * 4 + 2];
          s3 += red[(row_l * 8 + w8) * 4 + 3];
        }
        float mu_r = s0 * (1.f / 1024.f);
        float mu_i = s2 * (1.f / 1024.f);
        stats[row_l * 4 + 0] = mu_r;
        stats[row_l * 4 + 1] = rsqrtf(s1 * (1.f / 1024.f) - mu_r * mu_r + EPS);
        stats[row_l * 4 + 2] = mu_i;
        stats[row_l * 4 + 3] = rsqrtf(s3 * (1.f / 1024.f) - mu_i * mu_i + EPS);
      }
  }
  __syncthreads();

  // ---- P2c: apply LN, coalesced f32x4 writes of both outputs ----
  {
    int row = tid >> 4, cg = tid & 15;
    float mu_r = stats[row * 4 + 0], rd_r = stats[row * 4 + 1];
    float mu_i = stats[row * 4 + 2], rd_i = stats[row * 4 + 3];
    float* orp = outR + (row0 + row) * D;
    float* oip = outI + (row0 + row) * D;
#pragma unroll
    for (int v = 0; v < 16; ++v) {
      int col = v * 64 + cg * 4;
      H2x4 hv;
      hv.v = *(const s16x8*)&stash[row * PAD + col];
      f32x4 w4 = *(const f32x4*)(lw + col);
      f32x4 b4 = *(const f32x4*)(lb + col);
      f32x4 o_r, o_i;
#pragma unroll
      for (int j = 0; j < 4; ++j) {
        float nr = __low2float(hv.h[j]), ni = __high2float(hv.h[j]);
        o_r[j] = (nr - mu_r) * rd_r * w4[j] + b4[j];
        o_i[j] = (ni - mu_i) * rd_i * w4[j] + b4[j];
      }
      *(f32x4*)(orp + col) = o_r;
      *(f32x4*)(oip + col) = o_i;
    }
  }
}

extern "C" void kernel_launch(void* const* d_in, const int* in_sizes, int n_in,
                              void* d_out, int out_size, void* d_ws, size_t ws_size,
                              hipStream_t stream) {
  const float* xr = (const float*)d_in[0];
  const float* xi = (const float*)d_in[1];
  const float* pm = (const float*)d_in[2];
  const float* cf = (const float*)d_in[3];
  const float* lw = (const float*)d_in[4];
  const float* lb = (const float*)d_in[5];
  float* outR = (float*)d_out;
  float* outI = outR + (size_t)M * D;
  u16* bt = (u16*)d_ws;  // 2 MB, GEMM-chunk layout

  k_prep<<<dim3(32, 32), dim3(32, 8), 0, stream>>>(pm, bt);
  k_fused<<<M / R, 512, 0, stream>>>(xr, xi, bt, cf, lw, lb, outR, outI);
}